// Round 7
// baseline (213.467 us; speedup 1.0000x reference)
//
#include <hip/hip_runtime.h>
#include <hip/hip_bf16.h>
#include <stdint.h>

#define NR 384          // total rows
#define DD 73728        // C*H*W
#define PDV 16          // N_PARTS * N_DATASETS
#define BSV 192         // batch size
#define KSPLIT 256      // split-K factor (1536 blocks = 6/CU)
#define KCH 288         // DD / KSPLIT
#define BK 32           // K-tile per iteration
#define NIT 9           // KCH / BK
#define RS 40           // LDS row stride bf16 (80 B = 20 banks, 16B-aligned)

typedef __bf16 bf16;
typedef __attribute__((ext_vector_type(4))) __bf16 bf16x4;
typedef __attribute__((ext_vector_type(8))) __bf16 bf16x8;
typedef __attribute__((ext_vector_type(4))) float f32x4;

// ---------------------------------------------------------------- kernel 1
// Fused demean + cast + partial Gram, software-pipelined:
//   M slice staged to LDS once; X prefetched to registers one iter ahead;
//   demean+cvt at ds_write time (once per element); diagonal tiles skip B.
// KSPLIT=256 -> 6 blocks/CU co-resident: cross-block overlap hides the
// load->write_tiles latency that 3 blocks/CU couldn't (R6 post-mortem).
__global__ __launch_bounds__(256, 3) void k_gram(const float* __restrict__ X,
                                                 const float* __restrict__ M,
                                                 float* __restrict__ Gp) {
    __shared__ float msh[4 * KCH];     // 4.6 KB: this block's M k-slice
    __shared__ bf16 ash[128 * RS];     // 10 KB
    __shared__ bf16 bsh[128 * RS];     // 10 KB
    const int tid  = threadIdx.x;
    const int lane = tid & 63;
    const int w    = tid >> 6;
    const int quad = lane >> 4;
    const int l15  = lane & 15;
    const int wm   = w & 1, wn = w >> 1;
    const int srow = tid >> 3;         // staging row base 0..31
    const int fseg = tid & 7;          // 16B segment within 128B row-chunk

    int tile = blockIdx.x % 6;
    int ks   = blockIdx.x / 6;
    int tm = (tile < 3) ? 0 : ((tile < 5) ? 1 : 2);
    int tn = (tile < 3) ? tile : ((tile < 5) ? (tile - 2) : 2);
    const bool diag = (tm == tn);
    const float* Xa = X + (size_t)(tm * 128) * DD;
    const float* Xb = X + (size_t)(tn * 128) * DD;
    const bf16* bbase = diag ? ash : bsh;
    size_t k0 = (size_t)ks * KCH;

    // ---- stage M slice once: 4 datasets x 288 floats (72 float4 each)
    for (int i = tid; i < 4 * 72; i += 256) {
        int ds = i / 72;
        int c  = (i - ds * 72) * 4;
        *(float4*)&msh[ds * KCH + c] = *(const float4*)(M + (size_t)ds * DD + k0 + c);
    }

    f32x4 acc[4][4];
#pragma unroll
    for (int i = 0; i < 4; ++i)
#pragma unroll
        for (int j = 0; j < 4; ++j) acc[i][j] = (f32x4){0.f, 0.f, 0.f, 0.f};

    float4 xa[4], xb[4];
    auto load_regs = [&](int it) {
        size_t gk = k0 + (size_t)it * BK + fseg * 4;
#pragma unroll
        for (int p = 0; p < 4; ++p) {
            int row = p * 32 + srow;
            xa[p] = *(const float4*)(Xa + (size_t)row * DD + gk);
            if (!diag) xb[p] = *(const float4*)(Xb + (size_t)row * DD + gk);
        }
    };
    auto write_tiles = [&](int it) {
        int kc = it * BK + fseg * 4;
#pragma unroll
        for (int p = 0; p < 4; ++p) {
            int row = p * 32 + srow;
            float4 m4 = *(const float4*)&msh[((row >> 2) & 3) * KCH + kc];
            bf16x4 za;
            za[0] = (bf16)(xa[p].x - m4.x); za[1] = (bf16)(xa[p].y - m4.y);
            za[2] = (bf16)(xa[p].z - m4.z); za[3] = (bf16)(xa[p].w - m4.w);
            *(bf16x4*)&ash[row * RS + fseg * 4] = za;
            if (!diag) {
                bf16x4 zb;
                zb[0] = (bf16)(xb[p].x - m4.x); zb[1] = (bf16)(xb[p].y - m4.y);
                zb[2] = (bf16)(xb[p].z - m4.z); zb[3] = (bf16)(xb[p].w - m4.w);
                *(bf16x4*)&bsh[row * RS + fseg * 4] = zb;
            }
        }
    };

    load_regs(0);
    __syncthreads();        // msh visible (and iter-0 loads drained)
    write_tiles(0);

    for (int it = 0; it < NIT; ++it) {
        __syncthreads();    // tile `it` published
        if (it + 1 < NIT) load_regs(it + 1);   // prefetch behind compute
        bf16x8 af[4], bfv[4];
#pragma unroll
        for (int i = 0; i < 4; ++i) {
            int r = wm * 64 + i * 16 + l15;
            af[i] = *(const bf16x8*)&ash[r * RS + quad * 8];
        }
#pragma unroll
        for (int j = 0; j < 4; ++j) {
            int r = wn * 64 + j * 16 + l15;
            bfv[j] = *(const bf16x8*)&bbase[r * RS + quad * 8];
        }
#pragma unroll
        for (int i = 0; i < 4; ++i)
#pragma unroll
            for (int j = 0; j < 4; ++j)
                acc[i][j] = __builtin_amdgcn_mfma_f32_16x16x32_bf16(
                    af[i], bfv[j], acc[i][j], 0, 0, 0);
        __syncthreads();    // reads of tile `it` done
        if (it + 1 < NIT) write_tiles(it + 1);
    }

    float* gp = Gp + ((size_t)(ks * 6 + tile) << 14);
#pragma unroll
    for (int i = 0; i < 4; ++i) {
        int lr0 = wm * 64 + i * 16 + quad * 4;
#pragma unroll
        for (int j = 0; j < 4; ++j) {
            int lc = wn * 64 + j * 16 + l15;
#pragma unroll
            for (int r = 0; r < 4; ++r)
                gp[(lr0 + r) * 128 + lc] = acc[i][j][r];
        }
    }
}

// ---------------------------------------------------------------- kernel 2
// Reduce partials -> full symmetric G + per-row inverse norm. Zeroes out[0].
__global__ __launch_bounds__(256) void k_red(const float* __restrict__ Gp,
                                             float* __restrict__ G,
                                             float* __restrict__ invn,
                                             float* __restrict__ out) {
    int t    = blockIdx.x * 256 + threadIdx.x;
    if (t == 0) out[0] = 0.0f;
    int tile = t >> 14;
    int idx  = t & 16383;
    int lr   = idx >> 7, lc = idx & 127;
    const float* p = Gp + ((size_t)tile << 14) + idx;
    float s = 0.0f;
#pragma unroll 8
    for (int ks = 0; ks < KSPLIT; ++ks) s += p[(size_t)ks * 98304];
    int tm = (tile < 3) ? 0 : ((tile < 5) ? 1 : 2);
    int tn = (tile < 3) ? tile : ((tile < 5) ? (tile - 2) : 2);
    int a = tm * 128 + lr, b = tn * 128 + lc;
    G[(size_t)a * NR + b] = s;
    G[(size_t)b * NR + a] = s;
    if (a == b) invn[a] = 1.0f / fmaxf(sqrtf(s), 1e-6f);
}

// ---------------------------------------------------------------- kernel 3
// One wave per row a: Ds[a] = sum_b mask*exp(S[a][b]); then lane 0 adds this
// row's 4 pair-slot terms  (-num + log(exp(num)+Ds[a]))  to out.
__global__ __launch_bounds__(256) void k_dsum(const float* __restrict__ G,
                                              const float* __restrict__ invn,
                                              float* __restrict__ out) {
    const int lane = threadIdx.x & 63;
    const int a    = blockIdx.x * 4 + (threadIdx.x >> 6);
    float ia  = invn[a];
    int arem  = a & 15;
    float acc = 0.0f;
    for (int b = lane; b < NR; b += 64) {
        float s = G[(size_t)a * NR + b] * ia * invn[b] * 10.0f;
        if ((b & 15) != arem) acc += expf(s);
    }
#pragma unroll
    for (int o = 32; o > 0; o >>= 1) acc += __shfl_down(acc, o);
    if (lane == 0) {
        float Dsa = acc;
        int pr[4];
        if (a < 16)       { pr[0] = 192 + a; pr[1] = a + 16;  pr[2] = a + 192; pr[3] = a + 368; }
        else if (a < 192) { pr[0] = 192 + a; pr[1] = a + 16;  pr[2] = a + 192; pr[3] = a - 16; }
        else if (a < 368) { pr[0] = a - 192; pr[1] = a + 16;  pr[2] = a - 192; pr[3] = a - 16; }
        else              { pr[0] = a - 192; pr[1] = a - 368; pr[2] = a - 192; pr[3] = a - 16; }
        float t = 0.0f;
#pragma unroll
        for (int s = 0; s < 4; ++s) {
            int b = pr[s];
            float num = G[(size_t)a * NR + b] * ia * invn[b] * 10.0f;
            t += -num + logf(expf(num) + Dsa);
        }
        atomicAdd(out, t * (1.0f / 576.0f));   // / (N_TRANSFORMS*3*BS)
    }
}

// ---------------------------------------------------------------- launch
extern "C" void kernel_launch(void* const* d_in, const int* in_sizes, int n_in,
                              void* d_out, int out_size, void* d_ws, size_t ws_size,
                              hipStream_t stream) {
    const float* X = (const float*)d_in[0];
    const float* M = (const float*)d_in[1];
    float* out = (float*)d_out;

    char* ws = (char*)d_ws;
    float* Gp   = (float*)ws;                                  // 100.7 MB
    float* G    = Gp + (size_t)KSPLIT * 6 * 16384;             // 590 KB
    float* invn = G + (size_t)NR * NR;

    k_gram<<<dim3(6 * KSPLIT), dim3(256), 0, stream>>>(X, M, Gp);
    k_red<<<dim3(384), dim3(256), 0, stream>>>(Gp, G, invn, out);
    k_dsum<<<dim3(NR / 4), dim3(256), 0, stream>>>(G, invn, out);
}

// Round 8
// 202.663 us; speedup vs baseline: 1.0533x; 1.0533x over previous
//
#include <hip/hip_runtime.h>
#include <hip/hip_bf16.h>
#include <stdint.h>

#define NR 384          // total rows
#define DD 73728        // C*H*W
#define PDV 16          // N_PARTS * N_DATASETS
#define BSV 192         // batch size
#define KSPLIT 128      // split-K factor (768 blocks)
#define KCH 576         // DD / KSPLIT
#define BK 32           // K-tile per iteration
#define NIT 18          // KCH / BK (even: loop unrolled by 2)
#define RS 40           // LDS row stride bf16 (80 B = 20 banks, 16B-aligned)

typedef __bf16 bf16;
typedef __attribute__((ext_vector_type(4))) __bf16 bf16x4;
typedef __attribute__((ext_vector_type(8))) __bf16 bf16x8;
typedef __attribute__((ext_vector_type(4))) float f32x4;

// ---------------------------------------------------------------- kernel 1
// Fused demean + cast + partial Gram.
// Depth-2 register pipeline: loads for iter it+2 issue at top of iter it,
// so the vmcnt wait in write_tiles(it+1) lands ~2 compute phases after
// issue (R7 post-mortem: depth-1 window too short for L2/L3 latency).
// XCD swizzle: 6 tile-blocks sharing a K-slice land on one XCD's L2.
__global__ __launch_bounds__(256, 3) void k_gram(const float* __restrict__ X,
                                                 const float* __restrict__ M,
                                                 float* __restrict__ Gp) {
    __shared__ float msh[4 * KCH];     // 9.2 KB: this block's M k-slice
    __shared__ bf16 ash[128 * RS];     // 10 KB
    __shared__ bf16 bsh[128 * RS];     // 10 KB
    const int tid  = threadIdx.x;
    const int lane = tid & 63;
    const int w    = tid >> 6;
    const int quad = lane >> 4;
    const int l15  = lane & 15;
    const int wm   = w & 1, wn = w >> 1;
    const int srow = tid >> 3;         // staging row base 0..31
    const int fseg = tid & 7;          // 16B segment within 128B row-chunk

    int xcd  = blockIdx.x & 7;
    int g    = blockIdx.x >> 3;
    int tile = g % 6;
    int ks   = xcd + 8 * (g / 6);      // 6 tiles of one ks share an XCD
    int tm = (tile < 3) ? 0 : ((tile < 5) ? 1 : 2);
    int tn = (tile < 3) ? tile : ((tile < 5) ? (tile - 2) : 2);
    const bool diag = (tm == tn);
    const float* Xa = X + (size_t)(tm * 128) * DD;
    const float* Xb = X + (size_t)(tn * 128) * DD;
    const bf16* bbase = diag ? ash : bsh;
    size_t k0 = (size_t)ks * KCH;

    // ---- stage M slice once: 4 datasets x 576 floats
    for (int i = tid; i < 4 * 144; i += 256) {
        int ds = i / 144;
        int c  = (i - ds * 144) * 4;
        *(float4*)&msh[ds * KCH + c] = *(const float4*)(M + (size_t)ds * DD + k0 + c);
    }

    f32x4 acc[4][4];
#pragma unroll
    for (int i = 0; i < 4; ++i)
#pragma unroll
        for (int j = 0; j < 4; ++j) acc[i][j] = (f32x4){0.f, 0.f, 0.f, 0.f};

    float4 xa0[4], xb0[4], xa1[4], xb1[4];   // two literal-indexed buffers
    auto load_regs = [&](int it, float4 (&xa)[4], float4 (&xb)[4]) {
        size_t gk = k0 + (size_t)it * BK + fseg * 4;
#pragma unroll
        for (int p = 0; p < 4; ++p) {
            int row = p * 32 + srow;
            xa[p] = *(const float4*)(Xa + (size_t)row * DD + gk);
            if (!diag) xb[p] = *(const float4*)(Xb + (size_t)row * DD + gk);
        }
    };
    auto write_tiles = [&](int it, float4 (&xa)[4], float4 (&xb)[4]) {
        int kc = it * BK + fseg * 4;
#pragma unroll
        for (int p = 0; p < 4; ++p) {
            int row = p * 32 + srow;
            float4 m4 = *(const float4*)&msh[((row >> 2) & 3) * KCH + kc];
            bf16x4 za;
            za[0] = (bf16)(xa[p].x - m4.x); za[1] = (bf16)(xa[p].y - m4.y);
            za[2] = (bf16)(xa[p].z - m4.z); za[3] = (bf16)(xa[p].w - m4.w);
            *(bf16x4*)&ash[row * RS + fseg * 4] = za;
            if (!diag) {
                bf16x4 zb;
                zb[0] = (bf16)(xb[p].x - m4.x); zb[1] = (bf16)(xb[p].y - m4.y);
                zb[2] = (bf16)(xb[p].z - m4.z); zb[3] = (bf16)(xb[p].w - m4.w);
                *(bf16x4*)&bsh[row * RS + fseg * 4] = zb;
            }
        }
    };
    auto compute = [&]() {
        bf16x8 af[4], bfv[4];
#pragma unroll
        for (int i = 0; i < 4; ++i) {
            int r = wm * 64 + i * 16 + l15;
            af[i] = *(const bf16x8*)&ash[r * RS + quad * 8];
        }
#pragma unroll
        for (int j = 0; j < 4; ++j) {
            int r = wn * 64 + j * 16 + l15;
            bfv[j] = *(const bf16x8*)&bbase[r * RS + quad * 8];
        }
#pragma unroll
        for (int i = 0; i < 4; ++i)
#pragma unroll
            for (int j = 0; j < 4; ++j)
                acc[i][j] = __builtin_amdgcn_mfma_f32_16x16x32_bf16(
                    af[i], bfv[j], acc[i][j], 0, 0, 0);
    };

    load_regs(0, xa0, xb0);
    load_regs(1, xa1, xb1);
    __syncthreads();                 // msh visible
    write_tiles(0, xa0, xb0);        // vmcnt waits only for load(0)

    for (int it = 0; it < NIT; it += 2) {
        __syncthreads();                                   // tile it published
        if (it + 2 < NIT) load_regs(it + 2, xa0, xb0);     // depth-2 prefetch
        compute();                                         // tile it
        __syncthreads();                                   // reads done
        write_tiles(it + 1, xa1, xb1);
        __syncthreads();                                   // tile it+1 published
        if (it + 3 < NIT) load_regs(it + 3, xa1, xb1);
        compute();                                         // tile it+1
        __syncthreads();                                   // reads done
        if (it + 2 < NIT) write_tiles(it + 2, xa0, xb0);
    }

    float* gp = Gp + ((size_t)(ks * 6 + tile) << 14);
#pragma unroll
    for (int i = 0; i < 4; ++i) {
        int lr0 = wm * 64 + i * 16 + quad * 4;
#pragma unroll
        for (int j = 0; j < 4; ++j) {
            int lc = wn * 64 + j * 16 + l15;
#pragma unroll
            for (int r = 0; r < 4; ++r)
                gp[(lr0 + r) * 128 + lc] = acc[i][j][r];
        }
    }
}

// ---------------------------------------------------------------- kernel 2
// Reduce partials -> full symmetric G + per-row inverse norm. Zeroes out[0].
__global__ __launch_bounds__(256) void k_red(const float* __restrict__ Gp,
                                             float* __restrict__ G,
                                             float* __restrict__ invn,
                                             float* __restrict__ out) {
    int t    = blockIdx.x * 256 + threadIdx.x;
    if (t == 0) out[0] = 0.0f;
    int tile = t >> 14;
    int idx  = t & 16383;
    int lr   = idx >> 7, lc = idx & 127;
    const float* p = Gp + ((size_t)tile << 14) + idx;
    float s = 0.0f;
#pragma unroll 8
    for (int ks = 0; ks < KSPLIT; ++ks) s += p[(size_t)ks * 98304];
    int tm = (tile < 3) ? 0 : ((tile < 5) ? 1 : 2);
    int tn = (tile < 3) ? tile : ((tile < 5) ? (tile - 2) : 2);
    int a = tm * 128 + lr, b = tn * 128 + lc;
    G[(size_t)a * NR + b] = s;
    G[(size_t)b * NR + a] = s;
    if (a == b) invn[a] = 1.0f / fmaxf(sqrtf(s), 1e-6f);
}

// ---------------------------------------------------------------- kernel 3
// One wave per row a: Ds[a] = sum_b mask*exp(S[a][b]); then lane 0 adds this
// row's 4 pair-slot terms  (-num + log(exp(num)+Ds[a]))  to out.
__global__ __launch_bounds__(256) void k_dsum(const float* __restrict__ G,
                                              const float* __restrict__ invn,
                                              float* __restrict__ out) {
    const int lane = threadIdx.x & 63;
    const int a    = blockIdx.x * 4 + (threadIdx.x >> 6);
    float ia  = invn[a];
    int arem  = a & 15;
    float acc = 0.0f;
    for (int b = lane; b < NR; b += 64) {
        float s = G[(size_t)a * NR + b] * ia * invn[b] * 10.0f;
        if ((b & 15) != arem) acc += expf(s);
    }
#pragma unroll
    for (int o = 32; o > 0; o >>= 1) acc += __shfl_down(acc, o);
    if (lane == 0) {
        float Dsa = acc;
        int pr[4];
        if (a < 16)       { pr[0] = 192 + a; pr[1] = a + 16;  pr[2] = a + 192; pr[3] = a + 368; }
        else if (a < 192) { pr[0] = 192 + a; pr[1] = a + 16;  pr[2] = a + 192; pr[3] = a - 16; }
        else if (a < 368) { pr[0] = a - 192; pr[1] = a + 16;  pr[2] = a - 192; pr[3] = a - 16; }
        else              { pr[0] = a - 192; pr[1] = a - 368; pr[2] = a - 192; pr[3] = a - 16; }
        float t = 0.0f;
#pragma unroll
        for (int s = 0; s < 4; ++s) {
            int b = pr[s];
            float num = G[(size_t)a * NR + b] * ia * invn[b] * 10.0f;
            t += -num + logf(expf(num) + Dsa);
        }
        atomicAdd(out, t * (1.0f / 576.0f));   // / (N_TRANSFORMS*3*BS)
    }
}

// ---------------------------------------------------------------- launch
extern "C" void kernel_launch(void* const* d_in, const int* in_sizes, int n_in,
                              void* d_out, int out_size, void* d_ws, size_t ws_size,
                              hipStream_t stream) {
    const float* X = (const float*)d_in[0];
    const float* M = (const float*)d_in[1];
    float* out = (float*)d_out;

    char* ws = (char*)d_ws;
    float* Gp   = (float*)ws;                                  // 50.3 MB
    float* G    = Gp + (size_t)KSPLIT * 6 * 16384;             // 590 KB
    float* invn = G + (size_t)NR * NR;

    k_gram<<<dim3(6 * KSPLIT), dim3(256), 0, stream>>>(X, M, Gp);
    k_red<<<dim3(384), dim3(256), 0, stream>>>(Gp, G, invn, out);
    k_dsum<<<dim3(NR / 4), dim3(256), 0, stream>>>(G, invn, out);
}

// Round 9
// 195.086 us; speedup vs baseline: 1.0942x; 1.0388x over previous
//
#include <hip/hip_runtime.h>
#include <hip/hip_bf16.h>
#include <stdint.h>

#define NR 384          // total rows
#define DD 73728        // C*H*W
#define PDV 16          // N_PARTS * N_DATASETS
#define BSV 192         // batch size
#define KSPLIT 128      // split-K factor (768 blocks = 3/CU, fully resident)
#define KCH 576         // DD / KSPLIT
#define BK 32           // K-tile per iteration
#define NIT 18          // KCH / BK
#define RS 40           // LDS row stride bf16 (80 B = 20 banks, 16B-aligned)

typedef __bf16 bf16;
typedef __attribute__((ext_vector_type(4))) __bf16 bf16x4;
typedef __attribute__((ext_vector_type(8))) __bf16 bf16x8;
typedef __attribute__((ext_vector_type(4))) float f32x4;

// ---------------------------------------------------------------- kernel 1
// Fused demean + cast + partial Gram.
// R8 post-mortem: 3-barrier phase structure SERIALIZED the VMEM (~2.2k cyc),
// LDS (~2.4k cyc) and MFMA (~1k cyc) pipes -> 9.4k cyc/iter. This version
// double-buffers LDS with ONE barrier per iter: ds_write(tile it+1) and
// ds_read+MFMA(tile it) co-schedule between the same barriers, so per-iter
// cost -> max(pipes) not sum. Also: single msh read per thread per iter
// (dataset id (srow>>2)&3 is p-invariant — R8 read it 4x redundantly).
__global__ __launch_bounds__(256, 3) void k_gram(const float* __restrict__ X,
                                                 const float* __restrict__ M,
                                                 float* __restrict__ Gp) {
    __shared__ float msh[4 * KCH];       // 9.2 KB
    __shared__ bf16 ash[2][128 * RS];    // 20 KB
    __shared__ bf16 bsh[2][128 * RS];    // 20 KB  (total 49.2 KB, 3/CU OK)
    const int tid  = threadIdx.x;
    const int lane = tid & 63;
    const int w    = tid >> 6;
    const int quad = lane >> 4;
    const int l15  = lane & 15;
    const int wm   = w & 1, wn = w >> 1;
    const int srow = tid >> 3;           // staging row base 0..31
    const int fseg = tid & 7;            // 16B segment within 128B row-chunk
    const int mds  = (srow >> 2) & 3;    // dataset id (same for all p)

    int xcd  = blockIdx.x & 7;
    int g    = blockIdx.x >> 3;
    int tile = g % 6;
    int ks   = xcd + 8 * (g / 6);        // 6 tiles of one ks share an XCD
    int tm = (tile < 3) ? 0 : ((tile < 5) ? 1 : 2);
    int tn = (tile < 3) ? tile : ((tile < 5) ? (tile - 2) : 2);
    const bool diag = (tm == tn);
    const float* Xa = X + (size_t)(tm * 128) * DD;
    const float* Xb = X + (size_t)(tn * 128) * DD;
    size_t k0 = (size_t)ks * KCH;

    // ---- stage M slice once: 4 datasets x 576 floats
    for (int i = tid; i < 4 * 144; i += 256) {
        int ds = i / 144;
        int c  = (i - ds * 144) * 4;
        *(float4*)&msh[ds * KCH + c] = *(const float4*)(M + (size_t)ds * DD + k0 + c);
    }

    f32x4 acc[4][4];
#pragma unroll
    for (int i = 0; i < 4; ++i)
#pragma unroll
        for (int j = 0; j < 4; ++j) acc[i][j] = (f32x4){0.f, 0.f, 0.f, 0.f};

    float4 xa[4], xb[4];                 // single register buffer
    auto load_regs = [&](int it) {
        size_t gk = k0 + (size_t)it * BK + fseg * 4;
#pragma unroll
        for (int p = 0; p < 4; ++p) {
            int row = p * 32 + srow;
            xa[p] = *(const float4*)(Xa + (size_t)row * DD + gk);
            if (!diag) xb[p] = *(const float4*)(Xb + (size_t)row * DD + gk);
        }
    };
    auto write_tiles = [&](int it, int buf) {
        int kc = it * BK + fseg * 4;
        float4 m4 = *(const float4*)&msh[mds * KCH + kc];   // ONE read, all p
#pragma unroll
        for (int p = 0; p < 4; ++p) {
            int row = p * 32 + srow;
            bf16x4 za;
            za[0] = (bf16)(xa[p].x - m4.x); za[1] = (bf16)(xa[p].y - m4.y);
            za[2] = (bf16)(xa[p].z - m4.z); za[3] = (bf16)(xa[p].w - m4.w);
            *(bf16x4*)&ash[buf][row * RS + fseg * 4] = za;
            if (!diag) {
                bf16x4 zb;
                zb[0] = (bf16)(xb[p].x - m4.x); zb[1] = (bf16)(xb[p].y - m4.y);
                zb[2] = (bf16)(xb[p].z - m4.z); zb[3] = (bf16)(xb[p].w - m4.w);
                *(bf16x4*)&bsh[buf][row * RS + fseg * 4] = zb;
            }
        }
    };
    auto compute = [&](int buf) {
        const bf16* bb = diag ? ash[buf] : bsh[buf];
        bf16x8 af[4], bfv[4];
#pragma unroll
        for (int i = 0; i < 4; ++i) {
            int r = wm * 64 + i * 16 + l15;
            af[i] = *(const bf16x8*)&ash[buf][r * RS + quad * 8];
        }
#pragma unroll
        for (int j = 0; j < 4; ++j) {
            int r = wn * 64 + j * 16 + l15;
            bfv[j] = *(const bf16x8*)&bb[r * RS + quad * 8];
        }
#pragma unroll
        for (int i = 0; i < 4; ++i)
#pragma unroll
            for (int j = 0; j < 4; ++j)
                acc[i][j] = __builtin_amdgcn_mfma_f32_16x16x32_bf16(
                    af[i], bfv[j], acc[i][j], 0, 0, 0);
    };

    load_regs(0);
    __syncthreads();              // msh visible
    write_tiles(0, 0);            // vmcnt drains load(0) only
    load_regs(1);
    __syncthreads();              // L[0] published

    for (int it = 0; it < NIT; ++it) {
        int buf = it & 1;
        if (it + 1 < NIT) {
            write_tiles(it + 1, buf ^ 1);    // overlaps compute below
            if (it + 2 < NIT) load_regs(it + 2);
        }
        compute(buf);
        __syncthreads();          // publishes L[buf^1]; frees L[buf]
    }

    float* gp = Gp + ((size_t)(ks * 6 + tile) << 14);
#pragma unroll
    for (int i = 0; i < 4; ++i) {
        int lr0 = wm * 64 + i * 16 + quad * 4;
#pragma unroll
        for (int j = 0; j < 4; ++j) {
            int lc = wn * 64 + j * 16 + l15;
#pragma unroll
            for (int r = 0; r < 4; ++r)
                gp[(lr0 + r) * 128 + lc] = acc[i][j][r];
        }
    }
}

// ---------------------------------------------------------------- kernel 2
// Reduce partials -> full symmetric G + per-row inverse norm. Zeroes out[0].
__global__ __launch_bounds__(256) void k_red(const float* __restrict__ Gp,
                                             float* __restrict__ G,
                                             float* __restrict__ invn,
                                             float* __restrict__ out) {
    int t    = blockIdx.x * 256 + threadIdx.x;
    if (t == 0) out[0] = 0.0f;
    int tile = t >> 14;
    int idx  = t & 16383;
    int lr   = idx >> 7, lc = idx & 127;
    const float* p = Gp + ((size_t)tile << 14) + idx;
    float s = 0.0f;
#pragma unroll 8
    for (int ks = 0; ks < KSPLIT; ++ks) s += p[(size_t)ks * 98304];
    int tm = (tile < 3) ? 0 : ((tile < 5) ? 1 : 2);
    int tn = (tile < 3) ? tile : ((tile < 5) ? (tile - 2) : 2);
    int a = tm * 128 + lr, b = tn * 128 + lc;
    G[(size_t)a * NR + b] = s;
    G[(size_t)b * NR + a] = s;
    if (a == b) invn[a] = 1.0f / fmaxf(sqrtf(s), 1e-6f);
}

// ---------------------------------------------------------------- kernel 3
// One wave per row a: Ds[a] = sum_b mask*exp(S[a][b]); then lane 0 adds this
// row's 4 pair-slot terms  (-num + log(exp(num)+Ds[a]))  to out.
__global__ __launch_bounds__(256) void k_dsum(const float* __restrict__ G,
                                              const float* __restrict__ invn,
                                              float* __restrict__ out) {
    const int lane = threadIdx.x & 63;
    const int a    = blockIdx.x * 4 + (threadIdx.x >> 6);
    float ia  = invn[a];
    int arem  = a & 15;
    float acc = 0.0f;
    for (int b = lane; b < NR; b += 64) {
        float s = G[(size_t)a * NR + b] * ia * invn[b] * 10.0f;
        if ((b & 15) != arem) acc += expf(s);
    }
#pragma unroll
    for (int o = 32; o > 0; o >>= 1) acc += __shfl_down(acc, o);
    if (lane == 0) {
        float Dsa = acc;
        int pr[4];
        if (a < 16)       { pr[0] = 192 + a; pr[1] = a + 16;  pr[2] = a + 192; pr[3] = a + 368; }
        else if (a < 192) { pr[0] = 192 + a; pr[1] = a + 16;  pr[2] = a + 192; pr[3] = a - 16; }
        else if (a < 368) { pr[0] = a - 192; pr[1] = a + 16;  pr[2] = a - 192; pr[3] = a - 16; }
        else              { pr[0] = a - 192; pr[1] = a - 368; pr[2] = a - 192; pr[3] = a - 16; }
        float t = 0.0f;
#pragma unroll
        for (int s = 0; s < 4; ++s) {
            int b = pr[s];
            float num = G[(size_t)a * NR + b] * ia * invn[b] * 10.0f;
            t += -num + logf(expf(num) + Dsa);
        }
        atomicAdd(out, t * (1.0f / 576.0f));   // / (N_TRANSFORMS*3*BS)
    }
}

// ---------------------------------------------------------------- launch
extern "C" void kernel_launch(void* const* d_in, const int* in_sizes, int n_in,
                              void* d_out, int out_size, void* d_ws, size_t ws_size,
                              hipStream_t stream) {
    const float* X = (const float*)d_in[0];
    const float* M = (const float*)d_in[1];
    float* out = (float*)d_out;

    char* ws = (char*)d_ws;
    float* Gp   = (float*)ws;                                  // 50.3 MB
    float* G    = Gp + (size_t)KSPLIT * 6 * 16384;             // 590 KB
    float* invn = G + (size_t)NR * NR;

    k_gram<<<dim3(6 * KSPLIT), dim3(256), 0, stream>>>(X, M, Gp);
    k_red<<<dim3(384), dim3(256), 0, stream>>>(Gp, G, invn, out);
    k_dsum<<<dim3(NR / 4), dim3(256), 0, stream>>>(G, invn, out);
}